// Round 1
// baseline (1313.708 us; speedup 1.0000x reference)
//
#include <hip/hip_runtime.h>
#include <hip/hip_bf16.h>

#define NB   8
#define SS   2048
#define DD   1024
#define DFFN 4096
#define MTOT (NB*SS)   // 16384

typedef unsigned short u16;
typedef __attribute__((ext_vector_type(4))) float f32x4;
typedef __attribute__((ext_vector_type(8))) short bf16x8;
typedef __attribute__((ext_vector_type(4))) unsigned short u16x4;

__device__ __forceinline__ u16 f2bf(float f) {
  union { float f; unsigned u; } c; c.f = f;
  unsigned r = c.u + 0x7FFFu + ((c.u >> 16) & 1u);
  return (u16)(r >> 16);
}

// global -> LDS async copy, 16B per lane. LDS dest must be wave-uniform;
// HW writes lane i at lds_base + i*16. Use integer casts to build the
// addrspace pointers (generic LDS ptr offset lives in the low 32 bits).
__device__ __forceinline__ void gload16(const void* g, void* l) {
  __builtin_amdgcn_global_load_lds(
      (const __attribute__((address_space(1))) void*)(unsigned long long)g,
      (__attribute__((address_space(3))) void*)(unsigned)(unsigned long long)l,
      16, 0, 0);
}

// ---------------------------------------------------------------------------
// Generic GEMM-BT: C(MxN) = A(MxK) * B(NxK)^T  [+bias][*scale][*rowscale][gelu]
// m97 structure: 128x128 tile, BK=32, 256 threads (4 waves), each wave a
// 64x64 quadrant = 4x4 fragments of 16x16x32 MFMA.
// ---------------------------------------------------------------------------
template<int EBIAS, int EGELU, int ESCALE, int EROWSCALE, int OUTF32, int ETRANS, int CSKIP, int CK>
__global__ __launch_bounds__(256)
void gemm_bt(const u16* __restrict__ A, const u16* __restrict__ Bw,
             const float* __restrict__ bias, const float* __restrict__ rowscale,
             void* __restrict__ C,
             int M, int N, int K, int lda, int ldb, int ldc, float scale)
{
  const int tile_row0 = blockIdx.y * 128;
  const int tile_col0 = blockIdx.x * 128;
  if (CSKIP && tile_col0 > tile_row0 + 127) return;   // fully above causal diag

  __shared__ u16 Alds[128 * 32];
  __shared__ u16 Blds[128 * 32];

  const int tid  = threadIdx.x;
  const int wid  = tid >> 6;
  const int lane = tid & 63;
  const int wr = wid >> 1, wc = wid & 1;

  int nkt = K >> 5;
  if (CK) { int lim = (tile_row0 + 128) >> 5; if (lim < nkt) nkt = lim; }

  // staging: tile = 128 rows x 32 k (8 KB). 8 chunks of 1024B (16 rows each);
  // wave w stages chunks {w, w+4} for A and for B.
  const int arow = wid * 16 + (lane >> 2);   // row within tile for chunk wid
  const int kcol = (lane & 3) * 8;           // k offset (8 bf16 = 16 B)
  const char* gA0 = (const char*)(A + (size_t)(tile_row0 + arow) * lda + kcol);
  const char* gA1 = (const char*)(A + (size_t)(tile_row0 + arow + 64) * lda + kcol);
  const char* gB0 = (const char*)(Bw + (size_t)(tile_col0 + arow) * ldb + kcol);
  const char* gB1 = (const char*)(Bw + (size_t)(tile_col0 + arow + 64) * ldb + kcol);
  u16* lA0 = Alds + wid * 512;
  u16* lA1 = Alds + (wid + 4) * 512;
  u16* lB0 = Blds + wid * 512;
  u16* lB1 = Blds + (wid + 4) * 512;

  const int fr = lane & 15;          // A row / B col within 16
  const int ks = (lane >> 4) * 8;    // k segment (contiguous 8 bf16)
  const u16* ard = Alds + (size_t)(wr * 64 + fr) * 32 + ks;
  const u16* brd = Blds + (size_t)(wc * 64 + fr) * 32 + ks;

  f32x4 acc[4][4] = {};

  for (int kt = 0; kt < nkt; ++kt) {
    gload16(gA0, lA0); gload16(gA1, lA1);
    gload16(gB0, lB0); gload16(gB1, lB1);
    gA0 += 64; gA1 += 64; gB0 += 64; gB1 += 64;   // advance 32 bf16 in k
    __syncthreads();                                // drains vmcnt -> LDS ready

    bf16x8 af[4], bf[4];
#pragma unroll
    for (int m = 0; m < 4; ++m) af[m] = *(const bf16x8*)(ard + m * 512);
#pragma unroll
    for (int n = 0; n < 4; ++n) bf[n] = *(const bf16x8*)(brd + n * 512);
#pragma unroll
    for (int m = 0; m < 4; ++m)
#pragma unroll
      for (int n = 0; n < 4; ++n)
        acc[m][n] = __builtin_amdgcn_mfma_f32_16x16x32_bf16(af[m], bf[n], acc[m][n], 0, 0, 0);
    __syncthreads();                                // before next overwrite
  }

  // epilogue: C/D layout col = lane&15, row = (lane>>4)*4 + j  [m89-verified]
  const int r4 = (lane >> 4) * 4;
#pragma unroll
  for (int m = 0; m < 4; ++m) {
    const int row_base = tile_row0 + wr * 64 + m * 16 + r4;
#pragma unroll
    for (int n = 0; n < 4; ++n) {
      const int col = tile_col0 + wc * 64 + n * 16 + fr;
      float bia = EBIAS ? bias[col] : 0.0f;
#pragma unroll
      for (int j = 0; j < 4; ++j) {
        const int row = row_base + j;
        float x = acc[m][n][j];
        if (EBIAS)     x += bia;
        if (ESCALE)    x *= scale;
        if (EROWSCALE) x *= rowscale[row];
        if (EGELU)     x = 0.5f * x * (1.0f + erff(x * 0.70710678118f));
        if (OUTF32) {
          ((float*)C)[(size_t)row * ldc + col] = x;
        } else if (ETRANS) {
          // Vt[b][n][s]  (b = row/SS, s = row%SS)
          ((u16*)C)[(size_t)(row >> 11) * (DD * SS) + (size_t)col * SS + (row & (SS - 1))] = f2bf(x);
        } else {
          ((u16*)C)[(size_t)row * ldc + col] = f2bf(x);
        }
      }
    }
  }
}

// f32 -> bf16 convert, 4 elems/thread
__global__ void cvt_bf16_k(const float* __restrict__ in, u16* __restrict__ out, int n4) {
  int i = blockIdx.x * blockDim.x + threadIdx.x;
  if (i < n4) {
    float4 v = ((const float4*)in)[i];
    u16x4 o;
    o.x = f2bf(v.x); o.y = f2bf(v.y); o.z = f2bf(v.z); o.w = f2bf(v.w);
    ((u16x4*)out)[i] = o;
  }
}

// one wave per row: max, unnormalized exp (bf16), 1/sum. Zero-fills j>row.
__global__ void softmax_row_k(const float* __restrict__ sc, u16* __restrict__ P,
                              float* __restrict__ rinv) {
  const int m = blockIdx.x;
  const float* row = sc + (size_t)m * SS;
  u16* prow = P + (size_t)m * SS;
  const int L = m + 1;
  const int lane = threadIdx.x;
  float mx = -INFINITY;
  for (int j = lane; j < L; j += 64) mx = fmaxf(mx, row[j]);
#pragma unroll
  for (int o = 32; o >= 1; o >>= 1) mx = fmaxf(mx, __shfl_xor(mx, o));
  float s = 0.0f;
  for (int j = lane; j < L; j += 64) {
    float e = __expf(row[j] - mx);
    s += e;
    prow[j] = f2bf(e);
  }
#pragma unroll
  for (int o = 32; o >= 1; o >>= 1) s += __shfl_xor(s, o);
  if (lane == 0) rinv[m] = 1.0f / s;
  for (int j = L + lane; j < SS; j += 64) prow[j] = 0;
}

extern "C" void kernel_launch(void* const* d_in, const int* in_sizes, int n_in,
                              void* d_out, int out_size, void* d_ws, size_t ws_size,
                              hipStream_t stream) {
  const float* x  = (const float*)d_in[0];
  const float* Wq = (const float*)d_in[1];
  const float* bq = (const float*)d_in[2];
  const float* Wk = (const float*)d_in[3];
  const float* bk = (const float*)d_in[4];
  const float* Wv = (const float*)d_in[5];
  const float* bv = (const float*)d_in[6];
  const float* W1 = (const float*)d_in[7];
  const float* b1 = (const float*)d_in[8];
  const float* W2 = (const float*)d_in[9];
  const float* b2 = (const float*)d_in[10];

  char* ws = (char*)d_ws;
  // layout (bytes): peak ~174 MB
  u16*  xb   = (u16*)(ws);                                    // 32 MB (reused: attn_out)
  u16*  Wqb  = (u16*)(ws + 33554432);                         // 2 MB
  u16*  Wkb  = (u16*)(ws + 33554432 + 2097152);               // 2 MB
  u16*  Wvb  = (u16*)(ws + 33554432 + 2 * 2097152);           // 2 MB
  u16*  W1b  = (u16*)(ws + 33554432 + 3 * 2097152);           // 8 MB
  u16*  W2b  = (u16*)(ws + 33554432 + 3 * 2097152 + 8388608); // 8 MB
  u16*  Qb   = (u16*)(ws + 56623104);                         // 32 MB
  u16*  Kb   = (u16*)(ws + 90177536);                         // 32 MB
  u16*  Vtb  = (u16*)(ws + 123731968);                        // 32 MB
  float* rinv = (float*)(ws + 157286400);                     // 8 KB
  float* sc   = (float*)(ws + 157351936);                     // 16 MB (per-batch)
  u16*  P    = (u16*)(ws + 174129152);                        // 8 MB (per-batch)
  u16*  att  = xb;                                            // reuse region0
  u16*  h    = Qb;                                            // reuse Q+K (64 MB/chunk)

  // --- converts ---
  cvt_bf16_k<<<MTOT * DD / 4 / 256, 256, 0, stream>>>(x, xb, MTOT * DD / 4);
  cvt_bf16_k<<<DD * DD / 4 / 256, 256, 0, stream>>>(Wq, Wqb, DD * DD / 4);
  cvt_bf16_k<<<DD * DD / 4 / 256, 256, 0, stream>>>(Wk, Wkb, DD * DD / 4);
  cvt_bf16_k<<<DD * DD / 4 / 256, 256, 0, stream>>>(Wv, Wvb, DD * DD / 4);
  cvt_bf16_k<<<DFFN * DD / 4 / 256, 256, 0, stream>>>(W1, W1b, DFFN * DD / 4);
  cvt_bf16_k<<<DFFN * DD / 4 / 256, 256, 0, stream>>>(W2, W2b, DFFN * DD / 4);

  // --- QKV projections ---
  gemm_bt<1,0,0,0,0,0,0,0><<<dim3(DD/128, MTOT/128), 256, 0, stream>>>(
      xb, Wqb, bq, nullptr, (void*)Qb, MTOT, DD, DD, DD, DD, DD, 0.f);
  gemm_bt<1,0,0,0,0,0,0,0><<<dim3(DD/128, MTOT/128), 256, 0, stream>>>(
      xb, Wkb, bk, nullptr, (void*)Kb, MTOT, DD, DD, DD, DD, DD, 0.f);
  gemm_bt<1,0,0,0,0,1,0,0><<<dim3(DD/128, MTOT/128), 256, 0, stream>>>(
      xb, Wvb, bv, nullptr, (void*)Vtb, MTOT, DD, DD, DD, DD, DD, 0.f);

  // --- attention, per batch (scores/P scratch reused) ---
  for (int b = 0; b < NB; ++b) {
    gemm_bt<0,0,1,0,1,0,1,0><<<dim3(SS/128, SS/128), 256, 0, stream>>>(
        Qb + (size_t)b * SS * DD, Kb + (size_t)b * SS * DD, nullptr, nullptr,
        (void*)sc, SS, SS, DD, DD, DD, SS, 0.03125f);
    softmax_row_k<<<SS, 64, 0, stream>>>(sc, P, rinv);
    gemm_bt<0,0,0,1,0,0,0,1><<<dim3(DD/128, SS/128), 256, 0, stream>>>(
        P, Vtb + (size_t)b * DD * SS, nullptr, rinv,
        (void*)(att + (size_t)b * SS * DD), SS, DD, SS, SS, SS, DD, 0.f);
  }

  // --- MLP in 2 row-chunks (h reuses Q+K scratch) ---
  for (int c = 0; c < 2; ++c) {
    const int MC = MTOT / 2;  // 8192
    gemm_bt<1,1,0,0,0,0,0,0><<<dim3(DFFN/128, MC/128), 256, 0, stream>>>(
        att + (size_t)c * MC * DD, W1b, b1, nullptr, (void*)h,
        MC, DFFN, DD, DD, DD, DFFN, 0.f);
    gemm_bt<1,0,0,0,1,0,0,0><<<dim3(DD/128, MC/128), 256, 0, stream>>>(
        h, W2b, b2, nullptr, (void*)((float*)d_out + (size_t)c * MC * DD),
        MC, DD, DFFN, DFFN, DFFN, DD, 0.f);
  }
}

// Round 2
// 812.168 us; speedup vs baseline: 1.6175x; 1.6175x over previous
//
#include <hip/hip_runtime.h>
#include <hip/hip_bf16.h>

#define NB   8
#define SS   2048
#define DD   1024
#define DFFN 4096
#define MTOT (NB*SS)   // 16384

typedef unsigned short u16;
typedef __attribute__((ext_vector_type(4))) float f32x4;
typedef __attribute__((ext_vector_type(8))) short bf16x8;
typedef __attribute__((ext_vector_type(4))) unsigned short u16x4;
typedef __attribute__((ext_vector_type(8))) unsigned short u16x8;

__device__ __forceinline__ u16 f2bf(float f) {
  union { float f; unsigned u; } c; c.f = f;
  unsigned r = c.u + 0x7FFFu + ((c.u >> 16) & 1u);
  return (u16)(r >> 16);
}

// global -> LDS async copy, 16B per lane. LDS dest must be wave-uniform base;
// HW writes lane i at lds_base + i*16. Global source IS per-lane.
__device__ __forceinline__ void gload16(const void* g, void* l) {
  __builtin_amdgcn_global_load_lds(
      (const __attribute__((address_space(1))) void*)(unsigned long long)g,
      (__attribute__((address_space(3))) void*)(unsigned)(unsigned long long)l,
      16, 0, 0);
}

// ---------------------------------------------------------------------------
// 256x256 tile GEMM-BT: C = A(MxK) * B(NxK)^T, 512 threads (8 waves, 2x4),
// per-wave 128x64 output. BK=32, 4-deep LDS ring (4 x 32KB = 128KB), one
// s_barrier per K-step, counted vmcnt(8) (stages consumed 3 phases after
// issue -> loads never drained to 0 in the loop). LDS XOR-swizzle
// byte ^= ((row>>1)&3)<<4 (conflict-free b128 reads); global source is
// pre-swizzled so global_load_lds' linear dest yields swizzled content.
// ---------------------------------------------------------------------------
template<int EBIAS, int EGELU, int ESCALE, int EROWSCALE, int OUTMODE, int ETRANS, int CSKIP, int CK>
__global__ __launch_bounds__(512, 2)
void gemm256(const u16* __restrict__ A, const u16* __restrict__ B,
             const float* __restrict__ bias, const float* __restrict__ rowscale,
             void* __restrict__ C,
             int M, int N, int K, int lda, int ldb, int ldc, float scale,
             long long sA, long long sB, long long sC, int sRS)
{
  __shared__ __align__(1024) u16 smem[65536];   // 128 KB

  // bijective XCD swizzle over the x*y grid (z = batch)
  const int nwg = gridDim.x * gridDim.y;
  const int orig = blockIdx.y * gridDim.x + blockIdx.x;
  const int q = nwg >> 3, r = nwg & 7;
  const int xcd = orig & 7, pos = orig >> 3;
  const int wg = (xcd < r ? xcd * (q + 1) : r * (q + 1) + (xcd - r) * q) + pos;
  const int bx = wg % gridDim.x, by = wg / gridDim.x;
  const int row0 = by * 256, col0 = bx * 256;
  if (CSKIP && col0 > row0 + 255) return;

  const int z = blockIdx.z;
  A += (size_t)z * sA;
  B += (size_t)z * sB;

  int nkt = K >> 5;
  if (CK) { int lim = (row0 + 256) >> 5; if (lim < nkt) nkt = lim; }

  const int tid  = threadIdx.x;
  const int wid  = tid >> 6;
  const int lane = tid & 63;
  const int wr = wid >> 2, wc = wid & 3;

  // staging source (pre-swizzled): wave w covers rows w*16..w*16+15 of each
  // 128-row block; lane l -> row +(l>>2), col-unit (l&3)^((l>>3)&3) (8 bf16).
  const int srow = wid * 16 + (lane >> 2);
  const int sunit = (lane & 3) ^ ((lane >> 3) & 3);
  const char* gA = (const char*)A + ((size_t)(row0 + srow) * lda + sunit * 8) * 2;
  const char* gB = (const char*)B + ((size_t)(col0 + srow) * ldb + sunit * 8) * 2;
  char* lbase = (char*)smem;
  const size_t ldab = (size_t)128 * lda * 2;
  const size_t ldbb = (size_t)128 * ldb * 2;

  #define STAGE(kt) {                                                        \
    char* lb = lbase + ((kt) & 3) * 32768;                                   \
    size_t kb = (size_t)(kt) * 64;                                           \
    gload16(gA + kb,        lb + wid * 1024);                                \
    gload16(gA + kb + ldab, lb + 8192 + wid * 1024);                         \
    gload16(gB + kb,        lb + 16384 + wid * 1024);                        \
    gload16(gB + kb + ldbb, lb + 16384 + 8192 + wid * 1024);                 \
  }

  // LDS read offsets (swizzled)
  const int rd_off = (lane & 15) * 64 + ((lane >> 4) & 3) * 16;
  const int xm = ((lane >> 1) & 3) << 4;
  const int aoff = wr * 8192;
  const int boff = 16384 + wc * 4096;

  f32x4 acc[8][4] = {};

  // prologue: stage buffers 0,1,2 (nkt >= 8 for all our shapes)
  STAGE(0); STAGE(1); STAGE(2);
  asm volatile("s_waitcnt vmcnt(8)" ::: "memory");   // buf0 complete
  asm volatile("s_barrier" ::: "memory");

  for (int t = 0; t < nkt; ++t) {
    const int cb = (t & 3) * 32768;
    if (t + 3 < nkt) STAGE(t + 3);

    bf16x8 aR[8], bR[4];
#pragma unroll
    for (int m = 0; m < 8; ++m)
      aR[m] = *(const bf16x8*)((const char*)smem + ((cb + aoff + m * 1024 + rd_off) ^ xm));
#pragma unroll
    for (int n = 0; n < 4; ++n)
      bR[n] = *(const bf16x8*)((const char*)smem + ((cb + boff + n * 1024 + rd_off) ^ xm));

    __builtin_amdgcn_s_setprio(1);
#pragma unroll
    for (int m = 0; m < 8; ++m)
#pragma unroll
      for (int n = 0; n < 4; ++n)
        acc[m][n] = __builtin_amdgcn_mfma_f32_16x16x32_bf16(aR[m], bR[n], acc[m][n], 0, 0, 0);
    __builtin_amdgcn_s_setprio(0);

    // counted wait: buffer t+1 (staged 3 phases ago) complete; <=8 (2 bufs)
    // of newer stages stay in flight across the barrier.
    asm volatile("s_waitcnt vmcnt(8)" ::: "memory");
    asm volatile("s_barrier" ::: "memory");
  }
  #undef STAGE

  // epilogue: C/D layout col = lane&15, row = (lane>>4)*4 + j
  const int r4 = (lane >> 4) * 4;
#pragma unroll
  for (int n = 0; n < 4; ++n) {
    const int col = col0 + wc * 64 + n * 16 + (lane & 15);
    float bia = EBIAS ? bias[col] : 0.0f;
#pragma unroll
    for (int m = 0; m < 8; ++m) {
      const int rowb = row0 + wr * 128 + m * 16 + r4;
#pragma unroll
      for (int j = 0; j < 4; ++j) {
        const int row = rowb + j;
        float x = acc[m][n][j];
        if (EBIAS)     x += bia;
        if (ESCALE)    x *= scale;
        if (EROWSCALE) x *= rowscale[z * sRS + row];
        if (EGELU)     x = 0.5f * x * (1.0f + erff(x * 0.70710678118f));
        if (ETRANS) {
          // Vt[b][d][s]: b = row/SS, s = row%SS
          ((u16*)C)[(size_t)(row >> 11) * (DD * SS) + (size_t)col * SS + (row & (SS - 1))] = f2bf(x);
        } else if (OUTMODE == 1) {
          ((float*)C + (size_t)z * sC)[(size_t)row * ldc + col] = x;
        } else if (OUTMODE == 2) {
          ((_Float16*)C + (size_t)z * sC)[(size_t)row * ldc + col] = (_Float16)x;
        } else {
          ((u16*)C + (size_t)z * sC)[(size_t)row * ldc + col] = f2bf(x);
        }
      }
    }
  }
}

// f32 -> bf16 convert, 4 elems/thread
__global__ __launch_bounds__(256) void cvt_bf16_k(const float* __restrict__ in, u16* __restrict__ out, int n4) {
  int i = blockIdx.x * blockDim.x + threadIdx.x;
  if (i < n4) {
    float4 v = ((const float4*)in)[i];
    u16x4 o;
    o.x = f2bf(v.x); o.y = f2bf(v.y); o.z = f2bf(v.z); o.w = f2bf(v.w);
    ((u16x4*)out)[i] = o;
  }
}

// batched row softmax over f16 scores, in-place rewrite as unnormalized bf16 P
// (zero-filled above the causal diagonal), 1/sum per row. 4 rows per block.
__global__ __launch_bounds__(256) void softmax_k(u16* __restrict__ sc, float* __restrict__ rinv, int rows0) {
  const int widx = blockIdx.x * 4 + (threadIdx.x >> 6);
  const int lane = threadIdx.x & 63;
  u16* row = sc + (size_t)widx * SS;
  const int L = (widx & (SS - 1)) + 1;
  float mx = -1e30f;
  for (int k = 0; k < 4; ++k) {
    const int j0 = k * 512 + lane * 8;
    if (j0 < L) {
      u16x8 v = *(const u16x8*)(row + j0);
      int lim = L - j0; if (lim > 8) lim = 8;
#pragma unroll
      for (int e = 0; e < 8; ++e) {
        if (e < lim) { union { u16 u; _Float16 h; } c; c.u = v[e]; mx = fmaxf(mx, (float)c.h); }
      }
    }
  }
#pragma unroll
  for (int o = 32; o >= 1; o >>= 1) mx = fmaxf(mx, __shfl_xor(mx, o));
  float s = 0.0f;
  for (int k = 0; k < 4; ++k) {
    const int j0 = k * 512 + lane * 8;
    u16x8 v = *(const u16x8*)(row + j0);
    u16x8 w;
#pragma unroll
    for (int e = 0; e < 8; ++e) {
      const int j = j0 + e;
      float ev = 0.0f;
      if (j < L) { union { u16 u; _Float16 h; } c; c.u = v[e]; ev = __expf((float)c.h - mx); s += ev; }
      w[e] = f2bf(ev);
    }
    *(u16x8*)(row + j0) = w;
  }
#pragma unroll
  for (int o = 32; o >= 1; o >>= 1) s += __shfl_xor(s, o);
  if (lane == 0) rinv[rows0 + widx] = 1.0f / s;
}

extern "C" void kernel_launch(void* const* d_in, const int* in_sizes, int n_in,
                              void* d_out, int out_size, void* d_ws, size_t ws_size,
                              hipStream_t stream) {
  const float* x  = (const float*)d_in[0];
  const float* Wq = (const float*)d_in[1];
  const float* bq = (const float*)d_in[2];
  const float* Wk = (const float*)d_in[3];
  const float* bk = (const float*)d_in[4];
  const float* Wv = (const float*)d_in[5];
  const float* bv = (const float*)d_in[6];
  const float* W1 = (const float*)d_in[7];
  const float* b1 = (const float*)d_in[8];
  const float* W2 = (const float*)d_in[9];
  const float* b2 = (const float*)d_in[10];

  char* ws = (char*)d_ws;
  u16*  xb   = (u16*)(ws);                       // 32 MB (later: att)
  u16*  Wqb  = (u16*)(ws + 33554432);
  u16*  Wkb  = (u16*)(ws + 35651584);
  u16*  Wvb  = (u16*)(ws + 37748736);
  u16*  W1b  = (u16*)(ws + 39845888);
  u16*  W2b  = (u16*)(ws + 48234496);
  u16*  Qb   = (u16*)(ws + 56623104);            // 32 MB
  u16*  Kb   = (u16*)(ws + 90177536);            // 32 MB
  u16*  Vtb  = (u16*)(ws + 123731968);           // 32 MB
  float* rinv = (float*)(ws + 157286400);        // 64 KB
  u16*  big  = (u16*)(ws + 157351936);           // scores(f16)/P(bf16) region; later h
  u16*  att  = xb;

  const size_t base = 157351936ull;
  const size_t avail = ws_size > base ? ws_size - base : 0;
  int GB = 8; while (GB > 1 && (size_t)GB * 8388608ull > avail) GB >>= 1;
  int MC = 8192; while (MC > 2048 && (size_t)MC * 8192ull > avail) MC >>= 1;

  // --- converts ---
  cvt_bf16_k<<<MTOT * DD / 4 / 256, 256, 0, stream>>>(x, xb, MTOT * DD / 4);
  cvt_bf16_k<<<DD * DD / 4 / 256, 256, 0, stream>>>(Wq, Wqb, DD * DD / 4);
  cvt_bf16_k<<<DD * DD / 4 / 256, 256, 0, stream>>>(Wk, Wkb, DD * DD / 4);
  cvt_bf16_k<<<DD * DD / 4 / 256, 256, 0, stream>>>(Wv, Wvb, DD * DD / 4);
  cvt_bf16_k<<<DFFN * DD / 4 / 256, 256, 0, stream>>>(W1, W1b, DFFN * DD / 4);
  cvt_bf16_k<<<DFFN * DD / 4 / 256, 256, 0, stream>>>(W2, W2b, DFFN * DD / 4);

  // --- QKV projections (grid 4x64 = 256 blocks) ---
  gemm256<1,0,0,0,0,0,0,0><<<dim3(DD/256, MTOT/256), 512, 0, stream>>>(
      xb, Wqb, bq, nullptr, (void*)Qb, MTOT, DD, DD, DD, DD, DD, 0.f, 0, 0, 0, 0);
  gemm256<1,0,0,0,0,0,0,0><<<dim3(DD/256, MTOT/256), 512, 0, stream>>>(
      xb, Wkb, bk, nullptr, (void*)Kb, MTOT, DD, DD, DD, DD, DD, 0.f, 0, 0, 0, 0);
  gemm256<1,0,0,0,0,1,0,0><<<dim3(DD/256, MTOT/256), 512, 0, stream>>>(
      xb, Wvb, bv, nullptr, (void*)Vtb, MTOT, DD, DD, DD, DD, DD, 0.f, 0, 0, 0, 0);

  // --- attention, batched over z in groups of GB ---
  for (int b0 = 0; b0 < NB; b0 += GB) {
    // scores (f16, causal tile-skip)
    gemm256<0,0,1,0,2,0,1,0><<<dim3(SS/256, SS/256, GB), 512, 0, stream>>>(
        Qb + (size_t)b0 * SS * DD, Kb + (size_t)b0 * SS * DD, nullptr, nullptr,
        (void*)big, SS, SS, DD, DD, DD, SS, 0.03125f,
        (long long)SS * DD, (long long)SS * DD, (long long)SS * SS, 0);
    softmax_k<<<GB * SS / 4, 256, 0, stream>>>(big, rinv, b0 * SS);
    // PV: P(bf16, unnormalized) x Vt, rowscale = 1/sum, causal K-clip
    gemm256<0,0,0,1,0,0,0,1><<<dim3(DD/256, SS/256, GB), 512, 0, stream>>>(
        big, Vtb + (size_t)b0 * DD * SS, nullptr, rinv + (size_t)b0 * SS,
        (void*)(att + (size_t)b0 * SS * DD), SS, DD, SS, SS, SS, DD, 0.f,
        (long long)SS * SS, (long long)DD * SS, (long long)SS * DD, SS);
  }

  // --- MLP in chunks of MC rows (h reuses the scores region) ---
  for (int c = 0; c < MTOT / MC; ++c) {
    u16* h = big;
    gemm256<1,1,0,0,0,0,0,0><<<dim3(DFFN/256, MC/256), 512, 0, stream>>>(
        att + (size_t)c * MC * DD, W1b, b1, nullptr, (void*)h,
        MC, DFFN, DD, DD, DD, DFFN, 0.f, 0, 0, 0, 0);
    gemm256<1,0,0,0,1,0,0,0><<<dim3(DD/256, MC/256), 512, 0, stream>>>(
        h, W2b, b2, nullptr, (void*)((float*)d_out + (size_t)c * MC * DD),
        MC, DD, DFFN, DFFN, DFFN, DD, 0.f, 0, 0, 0, 0);
  }
}